// Round 2
// baseline (797.713 us; speedup 1.0000x reference)
//
#include <hip/hip_runtime.h>

#define NN 100000
#define IN_DIM 256
#define HID 32
#define OUT_DIM 12

// ---------------- degree / normalization ----------------
__global__ void k_init_deg(float* __restrict__ deg, int n) {
    int i = blockIdx.x * blockDim.x + threadIdx.x;
    if (i < n) deg[i] = 1.0f;   // self loop
}

__global__ void k_count(const int* __restrict__ dst, float* __restrict__ deg, int E) {
    int e = blockIdx.x * blockDim.x + threadIdx.x;
    if (e < E) atomicAdd(&deg[dst[e]], 1.0f);
}

__global__ void k_rsqrt(float* __restrict__ deg, int n) {
    int i = blockIdx.x * blockDim.x + threadIdx.x;
    if (i < n) deg[i] = rsqrtf(deg[i]);   // deg >= 1 always
}

// ---------------- GEMM1: hs1 = (x @ W1) * dis[row]; acc1 = hs1 ----------------
// block: 256 threads, 32 rows/block (100000 = 3125*32 exactly, no tail)
// thread: r = tid>>3 (row in tile), jg = tid&7 (4 output cols)
__global__ __launch_bounds__(256) void k_gemm1(
    const float* __restrict__ x, const float* __restrict__ W1,
    const float* __restrict__ dis, float* __restrict__ hs1, float* __restrict__ acc1)
{
    __shared__ float xs[32][68];     // pad 64->68: bank = (4r+k)%32, conflict-free
    __shared__ float wsh[64][32];
    const int tid = threadIdx.x;
    const int r = tid >> 3;
    const int jg = tid & 7;
    const int row0 = blockIdx.x * 32;
    float4 acc = make_float4(0.f, 0.f, 0.f, 0.f);

    for (int kc = 0; kc < IN_DIM / 64; ++kc) {
        // stage x tile: 32 rows x 64 cols = 512 float4
        #pragma unroll
        for (int rep = 0; rep < 2; ++rep) {
            int idx = rep * 256 + tid;          // float4 index
            int xr = idx >> 4;                  // 0..31
            int c4 = idx & 15;                  // 0..15
            float4 v = *(const float4*)&x[(size_t)(row0 + xr) * IN_DIM + kc * 64 + c4 * 4];
            *(float4*)&xs[xr][c4 * 4] = v;
        }
        // stage W chunk: 64 x 32 = 512 float4
        #pragma unroll
        for (int rep = 0; rep < 2; ++rep) {
            int idx = rep * 256 + tid;
            int wr = idx >> 3;                  // 0..63
            int c4 = idx & 7;                   // 0..7
            float4 v = *(const float4*)&W1[(size_t)(kc * 64 + wr) * HID + c4 * 4];
            *(float4*)&wsh[wr][c4 * 4] = v;
        }
        __syncthreads();
        #pragma unroll
        for (int k = 0; k < 64; ++k) {
            float xv = xs[r][k];
            float4 w = *(const float4*)&wsh[k][jg * 4];
            acc.x += xv * w.x; acc.y += xv * w.y; acc.z += xv * w.z; acc.w += xv * w.w;
        }
        __syncthreads();
    }
    int row = row0 + r;
    float s = dis[row];
    acc.x *= s; acc.y *= s; acc.z *= s; acc.w *= s;
    *(float4*)&hs1[(size_t)row * HID + jg * 4] = acc;
    *(float4*)&acc1[(size_t)row * HID + jg * 4] = acc;   // self-loop init
}

// ---------------- scatter1: acc1[d] += hs1[s], 32 threads/edge ----------------
__global__ __launch_bounds__(256) void k_scatter1(
    const int* __restrict__ src, const int* __restrict__ dst,
    const float* __restrict__ hs1, float* __restrict__ acc1, int E)
{
    long long tid = (long long)blockIdx.x * 256 + threadIdx.x;
    int e = (int)(tid >> 5);
    int j = (int)(tid & 31);
    if (e >= E) return;
    int s = 0, d = 0;
    if (j == 0) { s = src[e]; d = dst[e]; }
    s = __shfl(s, 0, 32);
    d = __shfl(d, 0, 32);
    atomicAdd(&acc1[(size_t)d * HID + j], hs1[(size_t)s * HID + j]);
}

// ---------------- GEMM2: v = relu(dis*acc1 + b1); hs2 = (v @ W2)*dis; acc2 = hs2 ----------------
__global__ __launch_bounds__(256) void k_gemm2(
    const float* __restrict__ acc1, const float* __restrict__ W2,
    const float* __restrict__ b1, const float* __restrict__ dis,
    float* __restrict__ hs2, float* __restrict__ acc2, int n)
{
    __shared__ float w2s[HID * OUT_DIM];
    __shared__ float b1s[HID];
    int tid = threadIdx.x;
    for (int i = tid; i < HID * OUT_DIM; i += 256) w2s[i] = W2[i];
    if (tid < HID) b1s[tid] = b1[tid];
    __syncthreads();
    int row = blockIdx.x * 256 + tid;
    if (row >= n) return;
    float ds = dis[row];
    float acc[OUT_DIM];
    #pragma unroll
    for (int j = 0; j < OUT_DIM; ++j) acc[j] = 0.f;
    #pragma unroll
    for (int k4 = 0; k4 < HID / 4; ++k4) {
        float4 v4 = *(const float4*)&acc1[(size_t)row * HID + k4 * 4];
        float vv[4] = { v4.x, v4.y, v4.z, v4.w };
        #pragma unroll
        for (int m = 0; m < 4; ++m) {
            int k = k4 * 4 + m;
            float v = fmaxf(ds * vv[m] + b1s[k], 0.f);
            #pragma unroll
            for (int j = 0; j < OUT_DIM; ++j) acc[j] += v * w2s[k * OUT_DIM + j];
        }
    }
    #pragma unroll
    for (int j = 0; j < OUT_DIM; ++j) {
        float o = acc[j] * ds;
        hs2[(size_t)row * OUT_DIM + j] = o;
        acc2[(size_t)row * OUT_DIM + j] = o;   // self-loop init
    }
}

// ---------------- scatter2: acc2[d] += hs2[s], 16 threads/edge (12 active) ----------------
__global__ __launch_bounds__(256) void k_scatter2(
    const int* __restrict__ src, const int* __restrict__ dst,
    const float* __restrict__ hs2, float* __restrict__ acc2, int E)
{
    long long tid = (long long)blockIdx.x * 256 + threadIdx.x;
    int e = (int)(tid >> 4);
    int j = (int)(tid & 15);
    if (e >= E) return;
    int s = 0, d = 0;
    if (j == 0) { s = src[e]; d = dst[e]; }
    s = __shfl(s, 0, 16);
    d = __shfl(d, 0, 16);
    if (j < OUT_DIM)
        atomicAdd(&acc2[(size_t)d * OUT_DIM + j], hs2[(size_t)s * OUT_DIM + j]);
}

// ---------------- final: out = dis*out + b2 (in place on d_out) ----------------
__global__ void k_final(float* __restrict__ acc2, const float* __restrict__ dis,
                        const float* __restrict__ b2, int n)
{
    int t = blockIdx.x * blockDim.x + threadIdx.x;
    if (t >= n * OUT_DIM) return;
    int i = t / OUT_DIM;
    int j = t - i * OUT_DIM;
    acc2[t] = dis[i] * acc2[t] + b2[j];
}

extern "C" void kernel_launch(void* const* d_in, const int* in_sizes, int n_in,
                              void* d_out, int out_size, void* d_ws, size_t ws_size,
                              hipStream_t stream)
{
    const float* x   = (const float*)d_in[0];
    const int*   ei  = (const int*)d_in[1];     // harness converts int64 -> int32
    const float* W1  = (const float*)d_in[2];
    const float* b1  = (const float*)d_in[3];
    const float* W2  = (const float*)d_in[4];
    const float* b2  = (const float*)d_in[5];
    float* out = (float*)d_out;

    const int N = NN;
    const int E = in_sizes[1] / 2;
    const int* srcp = ei;
    const int* dstp = ei + E;

    float* ws   = (float*)d_ws;
    float* dis  = ws;                          // N
    float* hs1  = dis + N;                     // N*32
    float* acc1 = hs1 + (size_t)N * HID;       // N*32
    float* hs2  = acc1 + (size_t)N * HID;      // N*12
    float* acc2 = out;                         // N*12, accumulate directly in d_out

    k_init_deg<<<(N + 255) / 256, 256, 0, stream>>>(dis, N);
    k_count<<<(E + 255) / 256, 256, 0, stream>>>(dstp, dis, E);
    k_rsqrt<<<(N + 255) / 256, 256, 0, stream>>>(dis, N);

    k_gemm1<<<N / 32, 256, 0, stream>>>(x, W1, dis, hs1, acc1);

    long long t1 = (long long)E * 32;
    k_scatter1<<<(int)((t1 + 255) / 256), 256, 0, stream>>>(srcp, dstp, hs1, acc1, E);

    k_gemm2<<<(N + 255) / 256, 256, 0, stream>>>(acc1, W2, b1, dis, hs2, acc2, N);

    long long t2 = (long long)E * 16;
    k_scatter2<<<(int)((t2 + 255) / 256), 256, 0, stream>>>(srcp, dstp, hs2, acc2, E);

    k_final<<<(N * OUT_DIM + 255) / 256, 256, 0, stream>>>(acc2, dis, b2, N);
}

// Round 3
// 610.790 us; speedup vs baseline: 1.3060x; 1.3060x over previous
//
#include <hip/hip_runtime.h>

#define NN 100000
#define IN_DIM 256
#define HID 32
#define OUT_DIM 12

// ====================== CSR build ======================
__global__ void k_zero(int* __restrict__ deg, int n) {
    int i = blockIdx.x * blockDim.x + threadIdx.x;
    if (i < n) deg[i] = 0;
}

__global__ void k_hist(const int* __restrict__ dst, int* __restrict__ deg, int E) {
    int e = blockIdx.x * blockDim.x + threadIdx.x;
    if (e < E) atomicAdd(&deg[dst[e]], 1);
}

__global__ __launch_bounds__(256) void k_blocksum(const int* __restrict__ deg,
                                                  int* __restrict__ bsum, int n) {
    __shared__ int s[256];
    int t = threadIdx.x;
    int i = blockIdx.x * 256 + t;
    s[t] = (i < n) ? deg[i] : 0;
    __syncthreads();
    for (int off = 128; off > 0; off >>= 1) {
        if (t < off) s[t] += s[t + off];
        __syncthreads();
    }
    if (t == 0) bsum[blockIdx.x] = s[0];
}

__global__ void k_scanpart(const int* __restrict__ bsum, int* __restrict__ boff, int nb) {
    __shared__ int s[512];
    int t = threadIdx.x;
    int own = (t < nb) ? bsum[t] : 0;
    s[t] = own;
    __syncthreads();
    for (int off = 1; off < 512; off <<= 1) {
        int v = (t >= off) ? s[t - off] : 0;
        __syncthreads();
        s[t] += v;
        __syncthreads();
    }
    if (t < nb) boff[t] = s[t] - own;   // exclusive prefix of block sums
}

__global__ __launch_bounds__(256) void k_scanfinal(
    const int* __restrict__ deg, const int* __restrict__ boff,
    int* __restrict__ row_start, int* __restrict__ cursor,
    float* __restrict__ dis, int n)
{
    __shared__ int s[256];
    int t = threadIdx.x;
    int i = blockIdx.x * 256 + t;
    int d = (i < n) ? deg[i] : 0;
    s[t] = d;
    __syncthreads();
    for (int off = 1; off < 256; off <<= 1) {
        int v = (t >= off) ? s[t - off] : 0;
        __syncthreads();
        s[t] += v;
        __syncthreads();
    }
    if (i < n) {
        int excl = boff[blockIdx.x] + s[t] - d;
        row_start[i] = excl;
        cursor[i]    = excl;
        dis[i] = rsqrtf((float)(d + 1));   // +1 self loop
    }
}

__global__ void k_fill(const int* __restrict__ src, const int* __restrict__ dst,
                       int* __restrict__ cursor, int* __restrict__ csr_src, int E) {
    int e = blockIdx.x * blockDim.x + threadIdx.x;
    if (e < E) {
        int pos = atomicAdd(&cursor[dst[e]], 1);
        csr_src[pos] = src[e];
    }
}

// ====================== GEMM1: hs1 = (x @ W1) * dis[row] ======================
__global__ __launch_bounds__(256) void k_gemm1(
    const float* __restrict__ x, const float* __restrict__ W1,
    const float* __restrict__ dis, float* __restrict__ hs1)
{
    __shared__ float xs[32][68];
    __shared__ float wsh[64][32];
    const int tid = threadIdx.x;
    const int r = tid >> 3;
    const int jg = tid & 7;
    const int row0 = blockIdx.x * 32;
    float4 acc = make_float4(0.f, 0.f, 0.f, 0.f);

    for (int kc = 0; kc < IN_DIM / 64; ++kc) {
        #pragma unroll
        for (int rep = 0; rep < 2; ++rep) {
            int idx = rep * 256 + tid;
            int xr = idx >> 4, c4 = idx & 15;
            float4 v = *(const float4*)&x[(size_t)(row0 + xr) * IN_DIM + kc * 64 + c4 * 4];
            *(float4*)&xs[xr][c4 * 4] = v;
        }
        #pragma unroll
        for (int rep = 0; rep < 2; ++rep) {
            int idx = rep * 256 + tid;
            int wr = idx >> 3, c4 = idx & 7;
            float4 v = *(const float4*)&W1[(size_t)(kc * 64 + wr) * HID + c4 * 4];
            *(float4*)&wsh[wr][c4 * 4] = v;
        }
        __syncthreads();
        #pragma unroll
        for (int k = 0; k < 64; ++k) {
            float xv = xs[r][k];
            float4 w = *(const float4*)&wsh[k][jg * 4];
            acc.x += xv * w.x; acc.y += xv * w.y; acc.z += xv * w.z; acc.w += xv * w.w;
        }
        __syncthreads();
    }
    int row = row0 + r;
    float s = dis[row];
    acc.x *= s; acc.y *= s; acc.z *= s; acc.w *= s;
    *(float4*)&hs1[(size_t)row * HID + jg * 4] = acc;
}

// ====================== agg1: pull-sum hs1 over in-edges + self ======================
// 32 lanes per node, 8 nodes per block
__global__ __launch_bounds__(256) void k_agg1(
    const int* __restrict__ csr_src, const int* __restrict__ row_start,
    const int* __restrict__ deg, const float* __restrict__ hs1,
    float* __restrict__ agg1, int n)
{
    int lane = threadIdx.x & 31;
    int node = blockIdx.x * 8 + (threadIdx.x >> 5);
    if (node >= n) return;
    int dg = deg[node];
    int st = row_start[node];
    float acc = hs1[(size_t)node * HID + lane];   // self loop
    for (int c0 = 0; c0 < dg; c0 += 32) {
        int e = c0 + lane;
        int sv = (e < dg) ? csr_src[st + e] : 0;
        int m = min(32, dg - c0);
        for (int i = 0; i < m; ++i) {
            int s = __shfl(sv, i, 32);
            acc += hs1[(size_t)s * HID + lane];
        }
    }
    agg1[(size_t)node * HID + lane] = acc;
}

// ====================== GEMM2: hs2 = (relu(dis*agg1 + b1) @ W2) * dis ======================
__global__ __launch_bounds__(256) void k_gemm2(
    const float* __restrict__ agg1, const float* __restrict__ W2,
    const float* __restrict__ b1, const float* __restrict__ dis,
    float* __restrict__ hs2, int n)
{
    __shared__ float w2s[HID * OUT_DIM];
    __shared__ float b1s[HID];
    int tid = threadIdx.x;
    for (int i = tid; i < HID * OUT_DIM; i += 256) w2s[i] = W2[i];
    if (tid < HID) b1s[tid] = b1[tid];
    __syncthreads();
    int row = blockIdx.x * 256 + tid;
    if (row >= n) return;
    float ds = dis[row];
    float acc[OUT_DIM];
    #pragma unroll
    for (int j = 0; j < OUT_DIM; ++j) acc[j] = 0.f;
    #pragma unroll
    for (int k4 = 0; k4 < HID / 4; ++k4) {
        float4 v4 = *(const float4*)&agg1[(size_t)row * HID + k4 * 4];
        float vv[4] = { v4.x, v4.y, v4.z, v4.w };
        #pragma unroll
        for (int m = 0; m < 4; ++m) {
            int k = k4 * 4 + m;
            float v = fmaxf(ds * vv[m] + b1s[k], 0.f);
            #pragma unroll
            for (int j = 0; j < OUT_DIM; ++j) acc[j] += v * w2s[k * OUT_DIM + j];
        }
    }
    #pragma unroll
    for (int j = 0; j < OUT_DIM; ++j)
        hs2[(size_t)row * OUT_DIM + j] = acc[j] * ds;
}

// ====================== agg2: out = dis*(self + pull-sum hs2) + b2 ======================
// 16 lanes per node (12 active on gather), 16 nodes per block
__global__ __launch_bounds__(256) void k_agg2(
    const int* __restrict__ csr_src, const int* __restrict__ row_start,
    const int* __restrict__ deg, const float* __restrict__ hs2,
    const float* __restrict__ dis, const float* __restrict__ b2,
    float* __restrict__ out, int n)
{
    int lane = threadIdx.x & 15;
    int node = blockIdx.x * 16 + (threadIdx.x >> 4);
    if (node >= n) return;
    int dg = deg[node];
    int st = row_start[node];
    float acc = (lane < OUT_DIM) ? hs2[(size_t)node * OUT_DIM + lane] : 0.f;  // self
    for (int c0 = 0; c0 < dg; c0 += 16) {
        int e = c0 + lane;
        int sv = (e < dg) ? csr_src[st + e] : 0;
        int m = min(16, dg - c0);
        for (int i = 0; i < m; ++i) {
            int s = __shfl(sv, i, 16);
            if (lane < OUT_DIM) acc += hs2[(size_t)s * OUT_DIM + lane];
        }
    }
    if (lane < OUT_DIM)
        out[(size_t)node * OUT_DIM + lane] = dis[node] * acc + b2[lane];
}

// ====================== launch ======================
extern "C" void kernel_launch(void* const* d_in, const int* in_sizes, int n_in,
                              void* d_out, int out_size, void* d_ws, size_t ws_size,
                              hipStream_t stream)
{
    const float* x  = (const float*)d_in[0];
    const int*   ei = (const int*)d_in[1];    // int64 inputs arrive as int32
    const float* W1 = (const float*)d_in[2];
    const float* b1 = (const float*)d_in[3];
    const float* W2 = (const float*)d_in[4];
    const float* b2 = (const float*)d_in[5];
    float* out = (float*)d_out;

    const int N = NN;
    const int E = in_sizes[1] / 2;
    const int* srcp = ei;
    const int* dstp = ei + E;
    const int NB = (N + 255) / 256;            // 391

    // workspace layout (ints first, then floats)
    int* i0        = (int*)d_ws;
    int* deg       = i0;                        // 100352
    int* row_start = i0 + 100352;
    int* cursor    = i0 + 200704;
    int* bsum      = i0 + 301056;               // 512
    int* boff      = i0 + 301568;               // 512
    int* csr_src   = i0 + 302080;               // E (3.2M)
    float* f0      = (float*)d_ws + 302080 + 3200000;
    float* dis     = f0;                        // 100352
    float* hs1     = dis + 100352;              // N*32
    float* agg1    = hs1 + (size_t)N * HID;     // N*32
    float* hs2     = agg1 + (size_t)N * HID;    // N*12

    // --- CSR build + normalization ---
    k_zero<<<NB, 256, 0, stream>>>(deg, N);
    k_hist<<<(E + 255) / 256, 256, 0, stream>>>(dstp, deg, E);
    k_blocksum<<<NB, 256, 0, stream>>>(deg, bsum, N);
    k_scanpart<<<1, 512, 0, stream>>>(bsum, boff, NB);
    k_scanfinal<<<NB, 256, 0, stream>>>(deg, boff, row_start, cursor, dis, N);
    k_fill<<<(E + 255) / 256, 256, 0, stream>>>(srcp, dstp, cursor, csr_src, E);

    // --- layer 1 ---
    k_gemm1<<<N / 32, 256, 0, stream>>>(x, W1, dis, hs1);
    k_agg1<<<(N + 7) / 8, 256, 0, stream>>>(csr_src, row_start, deg, hs1, agg1, N);

    // --- layer 2 ---
    k_gemm2<<<NB, 256, 0, stream>>>(agg1, W2, b1, dis, hs2, N);
    k_agg2<<<(N + 15) / 16, 256, 0, stream>>>(csr_src, row_start, deg, hs2, dis, b2, out, N);
}

// Round 4
// 414.283 us; speedup vs baseline: 1.9255x; 1.4743x over previous
//
#include <hip/hip_runtime.h>

#define NN 100000
#define IN_DIM 256
#define HID 32
#define OUT_DIM 12
#define NBK ((NN + 255) >> 8)   // 391 buckets of 256 dst-nodes
#define NBKP 512                 // padded
#define CE 4096                  // edges per k_bin block
#define EPT 16                   // edges per thread (256 threads)

// ====================== degree histogram + scan ======================
__global__ void k_zero(int* __restrict__ deg, int n) {
    int i = blockIdx.x * blockDim.x + threadIdx.x;
    if (i < n) deg[i] = 0;
}

__global__ void k_hist(const int* __restrict__ dst, int* __restrict__ deg, int E) {
    int e = blockIdx.x * blockDim.x + threadIdx.x;
    if (e < E) atomicAdd(&deg[dst[e]], 1);
}

__global__ __launch_bounds__(256) void k_blocksum(const int* __restrict__ deg,
                                                  int* __restrict__ bsum, int n) {
    __shared__ int s[256];
    int t = threadIdx.x;
    int i = blockIdx.x * 256 + t;
    s[t] = (i < n) ? deg[i] : 0;
    __syncthreads();
    for (int off = 128; off > 0; off >>= 1) {
        if (t < off) s[t] += s[t + off];
        __syncthreads();
    }
    if (t == 0) bsum[blockIdx.x] = s[0];
}

__global__ void k_scanpart(const int* __restrict__ bsum, int* __restrict__ boff, int nb) {
    __shared__ int s[512];
    int t = threadIdx.x;
    int own = (t < nb) ? bsum[t] : 0;
    s[t] = own;
    __syncthreads();
    for (int off = 1; off < 512; off <<= 1) {
        int v = (t >= off) ? s[t - off] : 0;
        __syncthreads();
        s[t] += v;
        __syncthreads();
    }
    if (t < nb) boff[t] = s[t] - own;
}

__global__ __launch_bounds__(256) void k_scanfinal(
    const int* __restrict__ deg, const int* __restrict__ boff,
    int* __restrict__ row_start, float* __restrict__ dis, int n)
{
    __shared__ int s[256];
    int t = threadIdx.x;
    int i = blockIdx.x * 256 + t;
    int d = (i < n) ? deg[i] : 0;
    s[t] = d;
    __syncthreads();
    for (int off = 1; off < 256; off <<= 1) {
        int v = (t >= off) ? s[t - off] : 0;
        __syncthreads();
        s[t] += v;
        __syncthreads();
    }
    if (i < n) {
        row_start[i] = boff[blockIdx.x] + s[t] - d;
        dis[i] = rsqrtf((float)(d + 1));   // +1 self loop
    }
}

__global__ void k_initgcur(const int* __restrict__ row_start, int* __restrict__ gcursor) {
    int t = blockIdx.x * blockDim.x + threadIdx.x;
    if (t < NBK) gcursor[t] = row_start[t << 8];
}

// ====================== pass 1: bin edges by 256-node dst range ======================
// entry = (src << 8) | (dst & 255); blocks write bucket-contiguous runs
__global__ __launch_bounds__(256) void k_bin(
    const int* __restrict__ src, const int* __restrict__ dst,
    int* __restrict__ gcursor, int* __restrict__ temp, int E)
{
    __shared__ int hist[NBKP];
    __shared__ int lstart[NBKP];
    __shared__ int lcur[NBKP];
    __shared__ int gbase[NBKP];
    __shared__ int lentry[CE];
    const int tid = threadIdx.x;
    const int base = blockIdx.x * CE;
    const int cnt = min(CE, E - base);

    int bk[EPT], en[EPT];
    #pragma unroll
    for (int i = 0; i < EPT; ++i) {
        int idx = i * 256 + tid;
        if (idx < cnt) {
            int s = src[base + idx];
            int d = dst[base + idx];
            bk[i] = d >> 8;
            en[i] = (s << 8) | (d & 255);
        } else bk[i] = -1;
    }
    hist[tid] = 0; hist[tid + 256] = 0;
    __syncthreads();
    #pragma unroll
    for (int i = 0; i < EPT; ++i)
        if (bk[i] >= 0) atomicAdd(&hist[bk[i]], 1);
    __syncthreads();
    // wave 0: exclusive scan of 512 counters (8 chunks of 64)
    if (tid < 64) {
        int run = 0;
        for (int c0 = 0; c0 < NBKP; c0 += 64) {
            int h = hist[c0 + tid];
            int v = h;
            #pragma unroll
            for (int off = 1; off < 64; off <<= 1) {
                int u = __shfl_up(v, off, 64);
                if (tid >= off) v += u;
            }
            lstart[c0 + tid] = run + v - h;
            run += __shfl(v, 63, 64);
        }
    }
    __syncthreads();
    // reserve global space per non-empty bucket
    for (int b0 = tid; b0 < NBK; b0 += 256) {
        int h = hist[b0];
        gbase[b0] = h ? atomicAdd(&gcursor[b0], h) : 0;
    }
    lcur[tid] = lstart[tid]; lcur[tid + 256] = lstart[tid + 256];
    __syncthreads();
    // place entries into LDS in bucket-sorted order
    #pragma unroll
    for (int i = 0; i < EPT; ++i)
        if (bk[i] >= 0) {
            int off = atomicAdd(&lcur[bk[i]], 1);
            lentry[off] = en[i];
        }
    __syncthreads();
    // copy out: consecutive j in same bucket -> consecutive global addresses
    for (int j = tid; j < cnt; j += 256) {
        int lo = 0, hi = NBK - 1;
        while (lo < hi) {
            int mid = (lo + hi + 1) >> 1;
            if (lstart[mid] <= j) lo = mid; else hi = mid - 1;
        }
        temp[gbase[lo] + (j - lstart[lo])] = lentry[j];
    }
}

// ====================== pass 2: exact per-node placement (XCD-local window) ======================
__global__ __launch_bounds__(256) void k_place(
    const int* __restrict__ temp, const int* __restrict__ row_start,
    int* __restrict__ csr_src, int n, int E)
{
    __shared__ int lcur[256];
    const int b = blockIdx.x;
    const int nbase = b << 8;
    const int tid = threadIdx.x;
    if (nbase + tid < n) lcur[tid] = row_start[nbase + tid];
    __syncthreads();
    const int rs = row_start[nbase];
    const int re = (nbase + 256 < n) ? row_start[nbase + 256] : E;
    for (int p = rs + tid; p < re; p += 256) {
        int e = temp[p];
        int pos = atomicAdd(&lcur[e & 255], 1);
        csr_src[pos] = e >> 8;
    }
}

// ====================== GEMM1: hs1 = (x @ W1) * dis[row] ======================
__global__ __launch_bounds__(256) void k_gemm1(
    const float* __restrict__ x, const float* __restrict__ W1,
    const float* __restrict__ dis, float* __restrict__ hs1)
{
    __shared__ float xs[32][68];
    __shared__ float wsh[64][32];
    const int tid = threadIdx.x;
    const int r = tid >> 3;
    const int jg = tid & 7;
    const int row0 = blockIdx.x * 32;
    float4 acc = make_float4(0.f, 0.f, 0.f, 0.f);

    for (int kc = 0; kc < IN_DIM / 64; ++kc) {
        #pragma unroll
        for (int rep = 0; rep < 2; ++rep) {
            int idx = rep * 256 + tid;
            int xr = idx >> 4, c4 = idx & 15;
            float4 v = *(const float4*)&x[(size_t)(row0 + xr) * IN_DIM + kc * 64 + c4 * 4];
            *(float4*)&xs[xr][c4 * 4] = v;
        }
        #pragma unroll
        for (int rep = 0; rep < 2; ++rep) {
            int idx = rep * 256 + tid;
            int wr = idx >> 3, c4 = idx & 7;
            float4 v = *(const float4*)&W1[(size_t)(kc * 64 + wr) * HID + c4 * 4];
            *(float4*)&wsh[wr][c4 * 4] = v;
        }
        __syncthreads();
        #pragma unroll
        for (int k = 0; k < 64; ++k) {
            float xv = xs[r][k];
            float4 w = *(const float4*)&wsh[k][jg * 4];
            acc.x += xv * w.x; acc.y += xv * w.y; acc.z += xv * w.z; acc.w += xv * w.w;
        }
        __syncthreads();
    }
    int row = row0 + r;
    float s = dis[row];
    acc.x *= s; acc.y *= s; acc.z *= s; acc.w *= s;
    *(float4*)&hs1[(size_t)row * HID + jg * 4] = acc;
}

// ====================== agg1: pull-sum hs1 over in-edges + self ======================
__global__ __launch_bounds__(256) void k_agg1(
    const int* __restrict__ csr_src, const int* __restrict__ row_start,
    const int* __restrict__ deg, const float* __restrict__ hs1,
    float* __restrict__ agg1, int n)
{
    int lane = threadIdx.x & 31;
    int node = blockIdx.x * 8 + (threadIdx.x >> 5);
    if (node >= n) return;
    int dg = deg[node];
    int st = row_start[node];
    float acc = hs1[(size_t)node * HID + lane];
    for (int c0 = 0; c0 < dg; c0 += 32) {
        int e = c0 + lane;
        int sv = (e < dg) ? csr_src[st + e] : 0;
        int m = min(32, dg - c0);
        for (int i = 0; i < m; ++i) {
            int s = __shfl(sv, i, 32);
            acc += hs1[(size_t)s * HID + lane];
        }
    }
    agg1[(size_t)node * HID + lane] = acc;
}

// ====================== GEMM2 ======================
__global__ __launch_bounds__(256) void k_gemm2(
    const float* __restrict__ agg1, const float* __restrict__ W2,
    const float* __restrict__ b1, const float* __restrict__ dis,
    float* __restrict__ hs2, int n)
{
    __shared__ float w2s[HID * OUT_DIM];
    __shared__ float b1s[HID];
    int tid = threadIdx.x;
    for (int i = tid; i < HID * OUT_DIM; i += 256) w2s[i] = W2[i];
    if (tid < HID) b1s[tid] = b1[tid];
    __syncthreads();
    int row = blockIdx.x * 256 + tid;
    if (row >= n) return;
    float ds = dis[row];
    float acc[OUT_DIM];
    #pragma unroll
    for (int j = 0; j < OUT_DIM; ++j) acc[j] = 0.f;
    #pragma unroll
    for (int k4 = 0; k4 < HID / 4; ++k4) {
        float4 v4 = *(const float4*)&agg1[(size_t)row * HID + k4 * 4];
        float vv[4] = { v4.x, v4.y, v4.z, v4.w };
        #pragma unroll
        for (int m = 0; m < 4; ++m) {
            int k = k4 * 4 + m;
            float v = fmaxf(ds * vv[m] + b1s[k], 0.f);
            #pragma unroll
            for (int j = 0; j < OUT_DIM; ++j) acc[j] += v * w2s[k * OUT_DIM + j];
        }
    }
    #pragma unroll
    for (int j = 0; j < OUT_DIM; ++j)
        hs2[(size_t)row * OUT_DIM + j] = acc[j] * ds;
}

// ====================== agg2 ======================
__global__ __launch_bounds__(256) void k_agg2(
    const int* __restrict__ csr_src, const int* __restrict__ row_start,
    const int* __restrict__ deg, const float* __restrict__ hs2,
    const float* __restrict__ dis, const float* __restrict__ b2,
    float* __restrict__ out, int n)
{
    int lane = threadIdx.x & 15;
    int node = blockIdx.x * 16 + (threadIdx.x >> 4);
    if (node >= n) return;
    int dg = deg[node];
    int st = row_start[node];
    float acc = (lane < OUT_DIM) ? hs2[(size_t)node * OUT_DIM + lane] : 0.f;
    for (int c0 = 0; c0 < dg; c0 += 16) {
        int e = c0 + lane;
        int sv = (e < dg) ? csr_src[st + e] : 0;
        int m = min(16, dg - c0);
        for (int i = 0; i < m; ++i) {
            int s = __shfl(sv, i, 16);
            if (lane < OUT_DIM) acc += hs2[(size_t)s * OUT_DIM + lane];
        }
    }
    if (lane < OUT_DIM)
        out[(size_t)node * OUT_DIM + lane] = dis[node] * acc + b2[lane];
}

// ====================== launch ======================
extern "C" void kernel_launch(void* const* d_in, const int* in_sizes, int n_in,
                              void* d_out, int out_size, void* d_ws, size_t ws_size,
                              hipStream_t stream)
{
    const float* x  = (const float*)d_in[0];
    const int*   ei = (const int*)d_in[1];    // int64 inputs arrive as int32
    const float* W1 = (const float*)d_in[2];
    const float* b1 = (const float*)d_in[3];
    const float* W2 = (const float*)d_in[4];
    const float* b2 = (const float*)d_in[5];
    float* out = (float*)d_out;

    const int N = NN;
    const int E = in_sizes[1] / 2;
    const int* srcp = ei;
    const int* dstp = ei + E;
    const int NB = (N + 255) / 256;            // 391

    // workspace layout
    int* i0        = (int*)d_ws;
    int* deg       = i0;                        // 100352
    int* row_start = i0 + 100352;               // 100352
    int* gcursor   = i0 + 200704;               // 512
    int* bsum      = i0 + 201216;               // 512
    int* boff      = i0 + 201728;               // 512
    int* csr_src   = i0 + 202240;               // E
    float* f0      = (float*)d_ws + 202240 + 3200000;
    float* dis     = f0;                        // 100352
    float* hs1     = dis + 100352;              // N*32  (also aliased as temp)
    float* agg1    = hs1 + (size_t)N * HID;     // N*32
    float* hs2     = agg1 + (size_t)N * HID;    // N*12
    int* temp      = (int*)hs1;                 // E ints, dead before k_gemm1

    // --- degree + scan + dis ---
    k_zero<<<NB, 256, 0, stream>>>(deg, N);
    k_hist<<<(E + 255) / 256, 256, 0, stream>>>(dstp, deg, E);
    k_blocksum<<<NB, 256, 0, stream>>>(deg, bsum, N);
    k_scanpart<<<1, 512, 0, stream>>>(bsum, boff, NB);
    k_scanfinal<<<NB, 256, 0, stream>>>(deg, boff, row_start, dis, N);

    // --- two-level CSR fill ---
    k_initgcur<<<2, 256, 0, stream>>>(row_start, gcursor);
    k_bin<<<(E + CE - 1) / CE, 256, 0, stream>>>(srcp, dstp, gcursor, temp, E);
    k_place<<<NBK, 256, 0, stream>>>(temp, row_start, csr_src, N, E);

    // --- layer 1 ---
    k_gemm1<<<N / 32, 256, 0, stream>>>(x, W1, dis, hs1);
    k_agg1<<<(N + 7) / 8, 256, 0, stream>>>(csr_src, row_start, deg, hs1, agg1, N);

    // --- layer 2 ---
    k_gemm2<<<NB, 256, 0, stream>>>(agg1, W2, b1, dis, hs2, N);
    k_agg2<<<(N + 15) / 16, 256, 0, stream>>>(csr_src, row_start, deg, hs2, dis, b2, out, N);
}

// Round 5
// 285.779 us; speedup vs baseline: 2.7914x; 1.4497x over previous
//
#include <hip/hip_runtime.h>

#define NN 100000
#define IN_DIM 256
#define HID 32
#define OUT_DIM 12
#define NBK ((NN + 255) >> 8)   // 391 buckets of 256 dst-nodes
#define NBKP 512                 // padded
#define CE 4096                  // edges per k_bin block
#define EPT 16                   // edges per thread (256 threads)
#define CAP 10240                // temp capacity per bucket (mean 8192, sigma ~90)

// ====================== zero bucket counters ======================
__global__ void k_zerob(int* __restrict__ bucket_cnt) {
    int i = threadIdx.x + blockIdx.x * blockDim.x;
    if (i < NBKP) bucket_cnt[i] = 0;
}

// ====================== pass 1: bin edges by 256-node dst range ======================
// entry = (src << 8) | (dst & 255); blocks write bucket-contiguous runs into
// fixed-capacity bucket slots of temp; bucket_cnt accumulates true bucket sizes.
__global__ __launch_bounds__(256) void k_bin(
    const int* __restrict__ src, const int* __restrict__ dst,
    int* __restrict__ bucket_cnt, int* __restrict__ temp, int E)
{
    __shared__ int hist[NBKP];
    __shared__ int lstart[NBKP];
    __shared__ int lcur[NBKP];
    __shared__ int gbase[NBKP];
    __shared__ int lentry[CE];
    const int tid = threadIdx.x;
    const int base = blockIdx.x * CE;
    const int cnt = min(CE, E - base);

    int bk[EPT], en[EPT];
    #pragma unroll
    for (int i = 0; i < EPT; ++i) {
        int idx = i * 256 + tid;
        if (idx < cnt) {
            int s = src[base + idx];
            int d = dst[base + idx];
            bk[i] = d >> 8;
            en[i] = (s << 8) | (d & 255);
        } else bk[i] = -1;
    }
    hist[tid] = 0; hist[tid + 256] = 0;
    __syncthreads();
    #pragma unroll
    for (int i = 0; i < EPT; ++i)
        if (bk[i] >= 0) atomicAdd(&hist[bk[i]], 1);
    __syncthreads();
    // wave 0: exclusive scan of 512 counters (8 chunks of 64)
    if (tid < 64) {
        int run = 0;
        for (int c0 = 0; c0 < NBKP; c0 += 64) {
            int h = hist[c0 + tid];
            int v = h;
            #pragma unroll
            for (int off = 1; off < 64; off <<= 1) {
                int u = __shfl_up(v, off, 64);
                if (tid >= off) v += u;
            }
            lstart[c0 + tid] = run + v - h;
            run += __shfl(v, 63, 64);
        }
    }
    __syncthreads();
    // reserve bucket-relative space per non-empty bucket
    for (int b0 = tid; b0 < NBK; b0 += 256) {
        int h = hist[b0];
        gbase[b0] = h ? atomicAdd(&bucket_cnt[b0], h) : 0;
    }
    lcur[tid] = lstart[tid]; lcur[tid + 256] = lstart[tid + 256];
    __syncthreads();
    // place entries into LDS in bucket-sorted order
    #pragma unroll
    for (int i = 0; i < EPT; ++i)
        if (bk[i] >= 0) {
            int off = atomicAdd(&lcur[bk[i]], 1);
            lentry[off] = en[i];
        }
    __syncthreads();
    // copy out: consecutive j in same bucket -> consecutive addresses
    for (int j = tid; j < cnt; j += 256) {
        int lo = 0, hi = NBK - 1;
        while (lo < hi) {
            int mid = (lo + hi + 1) >> 1;
            if (lstart[mid] <= j) lo = mid; else hi = mid - 1;
        }
        int idx = gbase[lo] + (j - lstart[lo]);
        if (idx < CAP)   // statistically impossible overflow; guard vs corruption
            temp[(size_t)lo * CAP + idx] = lentry[j];
    }
}

// ====================== scan 391 bucket counts -> bucket_base ======================
__global__ void k_scanb(const int* __restrict__ bucket_cnt, int* __restrict__ bucket_base, int nb) {
    __shared__ int s[512];
    int t = threadIdx.x;
    int own = (t < nb) ? bucket_cnt[t] : 0;
    s[t] = own;
    __syncthreads();
    for (int off = 1; off < 512; off <<= 1) {
        int v = (t >= off) ? s[t - off] : 0;
        __syncthreads();
        s[t] += v;
        __syncthreads();
    }
    if (t < nb) bucket_base[t] = s[t] - own;
}

// ====================== pass 2: per-node histogram + placement (XCD-local) ======================
// one block per bucket: emits deg, row_start, dis, and csr_src
__global__ __launch_bounds__(256) void k_place(
    const int* __restrict__ temp, const int* __restrict__ bucket_cnt,
    const int* __restrict__ bucket_base, int* __restrict__ csr_src,
    int* __restrict__ row_start, int* __restrict__ deg,
    float* __restrict__ dis, int n)
{
    __shared__ int cnt[256];
    __shared__ int s[256];
    __shared__ int pos[256];
    const int b = blockIdx.x;
    const int nbase = b << 8;
    const int tid = threadIdx.x;
    const int m = bucket_cnt[b];
    const size_t tbase = (size_t)b * CAP;
    cnt[tid] = 0;
    __syncthreads();
    for (int p = tid; p < m; p += 256)
        atomicAdd(&cnt[temp[tbase + p] & 255], 1);
    __syncthreads();
    int c = cnt[tid];
    s[tid] = c;
    __syncthreads();
    for (int off = 1; off < 256; off <<= 1) {
        int v = (tid >= off) ? s[tid - off] : 0;
        __syncthreads();
        s[tid] += v;
        __syncthreads();
    }
    int excl = s[tid] - c;
    int gb = bucket_base[b];
    if (nbase + tid < n) {
        row_start[nbase + tid] = gb + excl;
        deg[nbase + tid] = c;
        dis[nbase + tid] = rsqrtf((float)(c + 1));   // +1 self loop
    }
    pos[tid] = gb + excl;
    __syncthreads();
    for (int p = tid; p < m; p += 256) {
        int e = temp[tbase + p];
        int q = atomicAdd(&pos[e & 255], 1);
        csr_src[q] = e >> 8;
    }
}

// ====================== GEMM1: hs1 = (x @ W1) * dis[row] ======================
__global__ __launch_bounds__(256) void k_gemm1(
    const float* __restrict__ x, const float* __restrict__ W1,
    const float* __restrict__ dis, float* __restrict__ hs1)
{
    __shared__ float xs[32][68];
    __shared__ float wsh[64][32];
    const int tid = threadIdx.x;
    const int r = tid >> 3;
    const int jg = tid & 7;
    const int row0 = blockIdx.x * 32;
    float4 acc = make_float4(0.f, 0.f, 0.f, 0.f);

    for (int kc = 0; kc < IN_DIM / 64; ++kc) {
        #pragma unroll
        for (int rep = 0; rep < 2; ++rep) {
            int idx = rep * 256 + tid;
            int xr = idx >> 4, c4 = idx & 15;
            float4 v = *(const float4*)&x[(size_t)(row0 + xr) * IN_DIM + kc * 64 + c4 * 4];
            *(float4*)&xs[xr][c4 * 4] = v;
        }
        #pragma unroll
        for (int rep = 0; rep < 2; ++rep) {
            int idx = rep * 256 + tid;
            int wr = idx >> 3, c4 = idx & 7;
            float4 v = *(const float4*)&W1[(size_t)(kc * 64 + wr) * HID + c4 * 4];
            *(float4*)&wsh[wr][c4 * 4] = v;
        }
        __syncthreads();
        #pragma unroll
        for (int k = 0; k < 64; ++k) {
            float xv = xs[r][k];
            float4 w = *(const float4*)&wsh[k][jg * 4];
            acc.x += xv * w.x; acc.y += xv * w.y; acc.z += xv * w.z; acc.w += xv * w.w;
        }
        __syncthreads();
    }
    int row = row0 + r;
    float s = dis[row];
    acc.x *= s; acc.y *= s; acc.z *= s; acc.w *= s;
    *(float4*)&hs1[(size_t)row * HID + jg * 4] = acc;
}

// ====================== agg1: pull-sum hs1 over in-edges + self ======================
__global__ __launch_bounds__(256) void k_agg1(
    const int* __restrict__ csr_src, const int* __restrict__ row_start,
    const int* __restrict__ deg, const float* __restrict__ hs1,
    float* __restrict__ agg1, int n)
{
    int lane = threadIdx.x & 31;
    int node = blockIdx.x * 8 + (threadIdx.x >> 5);
    if (node >= n) return;
    int dg = deg[node];
    int st = row_start[node];
    float acc = hs1[(size_t)node * HID + lane];
    for (int c0 = 0; c0 < dg; c0 += 32) {
        int e = c0 + lane;
        int sv = (e < dg) ? csr_src[st + e] : 0;
        int m = min(32, dg - c0);
        for (int i = 0; i < m; ++i) {
            int s = __shfl(sv, i, 32);
            acc += hs1[(size_t)s * HID + lane];
        }
    }
    agg1[(size_t)node * HID + lane] = acc;
}

// ====================== GEMM2 ======================
__global__ __launch_bounds__(256) void k_gemm2(
    const float* __restrict__ agg1, const float* __restrict__ W2,
    const float* __restrict__ b1, const float* __restrict__ dis,
    float* __restrict__ hs2, int n)
{
    __shared__ float w2s[HID * OUT_DIM];
    __shared__ float b1s[HID];
    int tid = threadIdx.x;
    for (int i = tid; i < HID * OUT_DIM; i += 256) w2s[i] = W2[i];
    if (tid < HID) b1s[tid] = b1[tid];
    __syncthreads();
    int row = blockIdx.x * 256 + tid;
    if (row >= n) return;
    float ds = dis[row];
    float acc[OUT_DIM];
    #pragma unroll
    for (int j = 0; j < OUT_DIM; ++j) acc[j] = 0.f;
    #pragma unroll
    for (int k4 = 0; k4 < HID / 4; ++k4) {
        float4 v4 = *(const float4*)&agg1[(size_t)row * HID + k4 * 4];
        float vv[4] = { v4.x, v4.y, v4.z, v4.w };
        #pragma unroll
        for (int m = 0; m < 4; ++m) {
            int k = k4 * 4 + m;
            float v = fmaxf(ds * vv[m] + b1s[k], 0.f);
            #pragma unroll
            for (int j = 0; j < OUT_DIM; ++j) acc[j] += v * w2s[k * OUT_DIM + j];
        }
    }
    #pragma unroll
    for (int j = 0; j < OUT_DIM; ++j)
        hs2[(size_t)row * OUT_DIM + j] = acc[j] * ds;
}

// ====================== agg2 ======================
__global__ __launch_bounds__(256) void k_agg2(
    const int* __restrict__ csr_src, const int* __restrict__ row_start,
    const int* __restrict__ deg, const float* __restrict__ hs2,
    const float* __restrict__ dis, const float* __restrict__ b2,
    float* __restrict__ out, int n)
{
    int lane = threadIdx.x & 15;
    int node = blockIdx.x * 16 + (threadIdx.x >> 4);
    if (node >= n) return;
    int dg = deg[node];
    int st = row_start[node];
    float acc = (lane < OUT_DIM) ? hs2[(size_t)node * OUT_DIM + lane] : 0.f;
    for (int c0 = 0; c0 < dg; c0 += 16) {
        int e = c0 + lane;
        int sv = (e < dg) ? csr_src[st + e] : 0;
        int m = min(16, dg - c0);
        for (int i = 0; i < m; ++i) {
            int s = __shfl(sv, i, 16);
            if (lane < OUT_DIM) acc += hs2[(size_t)s * OUT_DIM + lane];
        }
    }
    if (lane < OUT_DIM)
        out[(size_t)node * OUT_DIM + lane] = dis[node] * acc + b2[lane];
}

// ====================== launch ======================
extern "C" void kernel_launch(void* const* d_in, const int* in_sizes, int n_in,
                              void* d_out, int out_size, void* d_ws, size_t ws_size,
                              hipStream_t stream)
{
    const float* x  = (const float*)d_in[0];
    const int*   ei = (const int*)d_in[1];    // int64 inputs arrive as int32
    const float* W1 = (const float*)d_in[2];
    const float* b1 = (const float*)d_in[3];
    const float* W2 = (const float*)d_in[4];
    const float* b2 = (const float*)d_in[5];
    float* out = (float*)d_out;

    const int N = NN;
    const int E = in_sizes[1] / 2;
    const int* srcp = ei;
    const int* dstp = ei + E;
    const int NB = (N + 255) / 256;            // 391

    // workspace layout
    int* i0          = (int*)d_ws;
    int* bucket_cnt  = i0;                      // 512
    int* bucket_base = i0 + 512;                // 512
    int* row_start   = i0 + 1024;               // 100352
    int* deg         = i0 + 101376;             // 100352
    int* csr_src     = i0 + 201728;             // E
    float* f0        = (float*)d_ws + 201728 + 3200000;
    float* dis       = f0;                      // 100352
    float* hs1       = dis + 100352;            // N*32 (aliased as temp pre-gemm1)
    float* agg1      = hs1 + (size_t)N * HID;   // N*32
    float* hs2       = agg1 + (size_t)N * HID;  // N*12
    int* temp        = (int*)hs1;               // NBK*CAP = 4.0M ints, fits hs1+agg1

    // --- CSR build (degrees derived in k_place; no global histogram) ---
    k_zerob<<<2, 256, 0, stream>>>(bucket_cnt);
    k_bin<<<(E + CE - 1) / CE, 256, 0, stream>>>(srcp, dstp, bucket_cnt, temp, E);
    k_scanb<<<1, 512, 0, stream>>>(bucket_cnt, bucket_base, NBK);
    k_place<<<NBK, 256, 0, stream>>>(temp, bucket_cnt, bucket_base,
                                     csr_src, row_start, deg, dis, N);

    // --- layer 1 ---
    k_gemm1<<<N / 32, 256, 0, stream>>>(x, W1, dis, hs1);
    k_agg1<<<(N + 7) / 8, 256, 0, stream>>>(csr_src, row_start, deg, hs1, agg1, N);

    // --- layer 2 ---
    k_gemm2<<<NB, 256, 0, stream>>>(agg1, W2, b1, dis, hs2, N);
    k_agg2<<<(N + 15) / 16, 256, 0, stream>>>(csr_src, row_start, deg, hs2, dis, b2, out, N);
}

// Round 6
// 214.546 us; speedup vs baseline: 3.7181x; 1.3320x over previous
//
#include <hip/hip_runtime.h>

#define NN 100000
#define IN_DIM 256
#define HID 32
#define OUT_DIM 12
#define NBK ((NN + 255) >> 8)   // 391 buckets of 256 dst-nodes
#define NBKP 512                 // padded
#define CE 4096                  // edges per k_bin block
#define EPT 16                   // edges per thread (256 threads)
#define CAP 10240                // temp capacity per bucket (mean 8192, sigma ~90)

// ====================== zero bucket counters ======================
__global__ void k_zerob(int* __restrict__ bucket_cnt) {
    int i = threadIdx.x + blockIdx.x * blockDim.x;
    if (i < NBKP) bucket_cnt[i] = 0;
}

// ====================== pass 1: bin edges by 256-node dst range ======================
__global__ __launch_bounds__(256) void k_bin(
    const int* __restrict__ src, const int* __restrict__ dst,
    int* __restrict__ bucket_cnt, int* __restrict__ temp, int E)
{
    __shared__ int hist[NBKP];
    __shared__ int lstart[NBKP];
    __shared__ int lcur[NBKP];
    __shared__ int gbase[NBKP];
    __shared__ int lentry[CE];
    const int tid = threadIdx.x;
    const int base = blockIdx.x * CE;
    const int cnt = min(CE, E - base);

    int bk[EPT], en[EPT];
    #pragma unroll
    for (int i = 0; i < EPT; ++i) {
        int idx = i * 256 + tid;
        if (idx < cnt) {
            int s = src[base + idx];
            int d = dst[base + idx];
            bk[i] = d >> 8;
            en[i] = (s << 8) | (d & 255);
        } else bk[i] = -1;
    }
    hist[tid] = 0; hist[tid + 256] = 0;
    __syncthreads();
    #pragma unroll
    for (int i = 0; i < EPT; ++i)
        if (bk[i] >= 0) atomicAdd(&hist[bk[i]], 1);
    __syncthreads();
    if (tid < 64) {
        int run = 0;
        for (int c0 = 0; c0 < NBKP; c0 += 64) {
            int h = hist[c0 + tid];
            int v = h;
            #pragma unroll
            for (int off = 1; off < 64; off <<= 1) {
                int u = __shfl_up(v, off, 64);
                if (tid >= off) v += u;
            }
            lstart[c0 + tid] = run + v - h;
            run += __shfl(v, 63, 64);
        }
    }
    __syncthreads();
    for (int b0 = tid; b0 < NBK; b0 += 256) {
        int h = hist[b0];
        gbase[b0] = h ? atomicAdd(&bucket_cnt[b0], h) : 0;
    }
    lcur[tid] = lstart[tid]; lcur[tid + 256] = lstart[tid + 256];
    __syncthreads();
    #pragma unroll
    for (int i = 0; i < EPT; ++i)
        if (bk[i] >= 0) {
            int off = atomicAdd(&lcur[bk[i]], 1);
            lentry[off] = en[i];
        }
    __syncthreads();
    for (int j = tid; j < cnt; j += 256) {
        int lo = 0, hi = NBK - 1;
        while (lo < hi) {
            int mid = (lo + hi + 1) >> 1;
            if (lstart[mid] <= j) lo = mid; else hi = mid - 1;
        }
        int idx = gbase[lo] + (j - lstart[lo]);
        if (idx < CAP)
            temp[(size_t)lo * CAP + idx] = lentry[j];
    }
}

// ====================== scan 391 bucket counts -> bucket_base ======================
__global__ void k_scanb(const int* __restrict__ bucket_cnt, int* __restrict__ bucket_base, int nb) {
    __shared__ int s[512];
    int t = threadIdx.x;
    int own = (t < nb) ? bucket_cnt[t] : 0;
    s[t] = own;
    __syncthreads();
    for (int off = 1; off < 512; off <<= 1) {
        int v = (t >= off) ? s[t - off] : 0;
        __syncthreads();
        s[t] += v;
        __syncthreads();
    }
    if (t < nb) bucket_base[t] = s[t] - own;
}

// ====================== pass 2: per-node histogram + placement ======================
__global__ __launch_bounds__(256) void k_place(
    const int* __restrict__ temp, const int* __restrict__ bucket_cnt,
    const int* __restrict__ bucket_base, int* __restrict__ csr_src,
    int* __restrict__ row_start, int* __restrict__ deg,
    float* __restrict__ dis, int n)
{
    __shared__ int cnt[256];
    __shared__ int s[256];
    __shared__ int pos[256];
    const int b = blockIdx.x;
    const int nbase = b << 8;
    const int tid = threadIdx.x;
    const int m = bucket_cnt[b];
    const size_t tbase = (size_t)b * CAP;
    cnt[tid] = 0;
    __syncthreads();
    for (int p = tid; p < m; p += 256)
        atomicAdd(&cnt[temp[tbase + p] & 255], 1);
    __syncthreads();
    int c = cnt[tid];
    s[tid] = c;
    __syncthreads();
    for (int off = 1; off < 256; off <<= 1) {
        int v = (tid >= off) ? s[tid - off] : 0;
        __syncthreads();
        s[tid] += v;
        __syncthreads();
    }
    int excl = s[tid] - c;
    int gb = bucket_base[b];
    if (nbase + tid < n) {
        row_start[nbase + tid] = gb + excl;
        deg[nbase + tid] = c;
        dis[nbase + tid] = rsqrtf((float)(c + 1));
    }
    pos[tid] = gb + excl;
    __syncthreads();
    for (int p = tid; p < m; p += 256) {
        int e = temp[tbase + p];
        int q = atomicAdd(&pos[e & 255], 1);
        csr_src[q] = e >> 8;
    }
}

// ====================== GEMM1: hs1 = (x @ W1) * dis[row] ======================
__global__ __launch_bounds__(256) void k_gemm1(
    const float* __restrict__ x, const float* __restrict__ W1,
    const float* __restrict__ dis, float* __restrict__ hs1)
{
    __shared__ float xs[32][68];
    __shared__ float wsh[64][32];
    const int tid = threadIdx.x;
    const int r = tid >> 3;
    const int jg = tid & 7;
    const int row0 = blockIdx.x * 32;
    float4 acc = make_float4(0.f, 0.f, 0.f, 0.f);

    for (int kc = 0; kc < IN_DIM / 64; ++kc) {
        #pragma unroll
        for (int rep = 0; rep < 2; ++rep) {
            int idx = rep * 256 + tid;
            int xr = idx >> 4, c4 = idx & 15;
            float4 v = *(const float4*)&x[(size_t)(row0 + xr) * IN_DIM + kc * 64 + c4 * 4];
            *(float4*)&xs[xr][c4 * 4] = v;
        }
        #pragma unroll
        for (int rep = 0; rep < 2; ++rep) {
            int idx = rep * 256 + tid;
            int wr = idx >> 3, c4 = idx & 7;
            float4 v = *(const float4*)&W1[(size_t)(kc * 64 + wr) * HID + c4 * 4];
            *(float4*)&wsh[wr][c4 * 4] = v;
        }
        __syncthreads();
        #pragma unroll
        for (int k = 0; k < 64; ++k) {
            float xv = xs[r][k];
            float4 w = *(const float4*)&wsh[k][jg * 4];
            acc.x += xv * w.x; acc.y += xv * w.y; acc.z += xv * w.z; acc.w += xv * w.w;
        }
        __syncthreads();
    }
    int row = row0 + r;
    float s = dis[row];
    acc.x *= s; acc.y *= s; acc.z *= s; acc.w *= s;
    *(float4*)&hs1[(size_t)row * HID + jg * 4] = acc;
}

// ====================== agg1: pull-sum, 4-way MLP unroll ======================
__global__ __launch_bounds__(256) void k_agg1(
    const int* __restrict__ csr_src, const int* __restrict__ row_start,
    const int* __restrict__ deg, const float* __restrict__ hs1,
    float* __restrict__ agg1, int n)
{
    int lane = threadIdx.x & 31;
    int node = blockIdx.x * 8 + (threadIdx.x >> 5);
    if (node >= n) return;
    int dg = deg[node];
    int st = row_start[node];
    float a0 = hs1[(size_t)node * HID + lane];   // self loop
    float a1 = 0.f, a2 = 0.f, a3 = 0.f;
    for (int c0 = 0; c0 < dg; c0 += 32) {
        int e = c0 + lane;
        int sv = (e < dg) ? csr_src[st + e] : 0;
        int m = min(32, dg - c0);
        int i = 0;
        for (; i + 4 <= m; i += 4) {
            int s0 = __shfl(sv, i,     32);
            int s1 = __shfl(sv, i + 1, 32);
            int s2 = __shfl(sv, i + 2, 32);
            int s3 = __shfl(sv, i + 3, 32);
            float v0 = hs1[(size_t)s0 * HID + lane];
            float v1 = hs1[(size_t)s1 * HID + lane];
            float v2 = hs1[(size_t)s2 * HID + lane];
            float v3 = hs1[(size_t)s3 * HID + lane];
            a0 += v0; a1 += v1; a2 += v2; a3 += v3;
        }
        for (; i < m; ++i) {
            int s = __shfl(sv, i, 32);
            a0 += hs1[(size_t)s * HID + lane];
        }
    }
    agg1[(size_t)node * HID + lane] = (a0 + a1) + (a2 + a3);
}

// ====================== GEMM2 ======================
__global__ __launch_bounds__(256) void k_gemm2(
    const float* __restrict__ agg1, const float* __restrict__ W2,
    const float* __restrict__ b1, const float* __restrict__ dis,
    float* __restrict__ hs2, int n)
{
    __shared__ float w2s[HID * OUT_DIM];
    __shared__ float b1s[HID];
    int tid = threadIdx.x;
    for (int i = tid; i < HID * OUT_DIM; i += 256) w2s[i] = W2[i];
    if (tid < HID) b1s[tid] = b1[tid];
    __syncthreads();
    int row = blockIdx.x * 256 + tid;
    if (row >= n) return;
    float ds = dis[row];
    float acc[OUT_DIM];
    #pragma unroll
    for (int j = 0; j < OUT_DIM; ++j) acc[j] = 0.f;
    #pragma unroll
    for (int k4 = 0; k4 < HID / 4; ++k4) {
        float4 v4 = *(const float4*)&agg1[(size_t)row * HID + k4 * 4];
        float vv[4] = { v4.x, v4.y, v4.z, v4.w };
        #pragma unroll
        for (int m = 0; m < 4; ++m) {
            int k = k4 * 4 + m;
            float v = fmaxf(ds * vv[m] + b1s[k], 0.f);
            #pragma unroll
            for (int j = 0; j < OUT_DIM; ++j) acc[j] += v * w2s[k * OUT_DIM + j];
        }
    }
    #pragma unroll
    for (int j = 0; j < OUT_DIM; ++j)
        hs2[(size_t)row * OUT_DIM + j] = acc[j] * ds;
}

// ====================== agg2: pull-sum, 4-way MLP unroll ======================
__global__ __launch_bounds__(256) void k_agg2(
    const int* __restrict__ csr_src, const int* __restrict__ row_start,
    const int* __restrict__ deg, const float* __restrict__ hs2,
    const float* __restrict__ dis, const float* __restrict__ b2,
    float* __restrict__ out, int n)
{
    int lane = threadIdx.x & 15;
    int node = blockIdx.x * 16 + (threadIdx.x >> 4);
    if (node >= n) return;
    int dg = deg[node];
    int st = row_start[node];
    float a0 = (lane < OUT_DIM) ? hs2[(size_t)node * OUT_DIM + lane] : 0.f;
    float a1 = 0.f, a2 = 0.f, a3 = 0.f;
    for (int c0 = 0; c0 < dg; c0 += 16) {
        int e = c0 + lane;
        int sv = (e < dg) ? csr_src[st + e] : 0;
        int m = min(16, dg - c0);
        int i = 0;
        for (; i + 4 <= m; i += 4) {
            int s0 = __shfl(sv, i,     16);
            int s1 = __shfl(sv, i + 1, 16);
            int s2 = __shfl(sv, i + 2, 16);
            int s3 = __shfl(sv, i + 3, 16);
            if (lane < OUT_DIM) {
                float v0 = hs2[(size_t)s0 * OUT_DIM + lane];
                float v1 = hs2[(size_t)s1 * OUT_DIM + lane];
                float v2 = hs2[(size_t)s2 * OUT_DIM + lane];
                float v3 = hs2[(size_t)s3 * OUT_DIM + lane];
                a0 += v0; a1 += v1; a2 += v2; a3 += v3;
            }
        }
        for (; i < m; ++i) {
            int s = __shfl(sv, i, 16);
            if (lane < OUT_DIM) a0 += hs2[(size_t)s * OUT_DIM + lane];
        }
    }
    if (lane < OUT_DIM)
        out[(size_t)node * OUT_DIM + lane] = dis[node] * ((a0 + a1) + (a2 + a3)) + b2[lane];
}

// ====================== launch ======================
extern "C" void kernel_launch(void* const* d_in, const int* in_sizes, int n_in,
                              void* d_out, int out_size, void* d_ws, size_t ws_size,
                              hipStream_t stream)
{
    const float* x  = (const float*)d_in[0];
    const int*   ei = (const int*)d_in[1];    // int64 inputs arrive as int32
    const float* W1 = (const float*)d_in[2];
    const float* b1 = (const float*)d_in[3];
    const float* W2 = (const float*)d_in[4];
    const float* b2 = (const float*)d_in[5];
    float* out = (float*)d_out;

    const int N = NN;
    const int E = in_sizes[1] / 2;
    const int* srcp = ei;
    const int* dstp = ei + E;
    const int NB = (N + 255) / 256;            // 391

    // workspace layout
    int* i0          = (int*)d_ws;
    int* bucket_cnt  = i0;                      // 512
    int* bucket_base = i0 + 512;                // 512
    int* row_start   = i0 + 1024;               // 100352
    int* deg         = i0 + 101376;             // 100352
    int* csr_src     = i0 + 201728;             // E
    float* f0        = (float*)d_ws + 201728 + 3200000;
    float* dis       = f0;                      // 100352
    float* hs1       = dis + 100352;            // N*32 (aliased as temp pre-gemm1)
    float* agg1      = hs1 + (size_t)N * HID;   // N*32
    float* hs2       = agg1 + (size_t)N * HID;  // N*12
    int* temp        = (int*)hs1;               // NBK*CAP = 4.0M ints

    // --- CSR build ---
    k_zerob<<<2, 256, 0, stream>>>(bucket_cnt);
    k_bin<<<(E + CE - 1) / CE, 256, 0, stream>>>(srcp, dstp, bucket_cnt, temp, E);
    k_scanb<<<1, 512, 0, stream>>>(bucket_cnt, bucket_base, NBK);
    k_place<<<NBK, 256, 0, stream>>>(temp, bucket_cnt, bucket_base,
                                     csr_src, row_start, deg, dis, N);

    // --- layer 1 ---
    k_gemm1<<<N / 32, 256, 0, stream>>>(x, W1, dis, hs1);
    k_agg1<<<(N + 7) / 8, 256, 0, stream>>>(csr_src, row_start, deg, hs1, agg1, N);

    // --- layer 2 ---
    k_gemm2<<<NB, 256, 0, stream>>>(agg1, W2, b1, dis, hs2, N);
    k_agg2<<<(N + 15) / 16, 256, 0, stream>>>(csr_src, row_start, deg, hs2, dis, b2, out, N);
}

// Round 7
// 201.680 us; speedup vs baseline: 3.9553x; 1.0638x over previous
//
#include <hip/hip_runtime.h>

#define NN 100000
#define IN_DIM 256
#define HID 32
#define OUT_DIM 12
#define NBK ((NN + 255) >> 8)   // 391 buckets of 256 dst-nodes
#define NBKP 512                 // padded
#define CE 4096                  // edges per k_bin block
#define EPT 16                   // edges per thread (256 threads)
#define CAP 10240                // temp capacity per bucket (mean 8192, sigma ~90)

// ====================== zero bucket counters ======================
__global__ void k_zerob(int* __restrict__ bucket_cnt) {
    int i = threadIdx.x + blockIdx.x * blockDim.x;
    if (i < NBKP) bucket_cnt[i] = 0;
}

// ====================== pass 1: bin edges by 256-node dst range ======================
// entry = (src << 8) | (dst & 255). Destination addresses are computed at
// placement time (laddr) -> copy-out is a coalesced LDS->global stream, no search.
__global__ __launch_bounds__(256) void k_bin(
    const int* __restrict__ src, const int* __restrict__ dst,
    int* __restrict__ bucket_cnt, int* __restrict__ temp, int E)
{
    __shared__ int hist[NBKP];
    __shared__ int lstart[NBKP];
    __shared__ int lcur[NBKP];
    __shared__ int gbase[NBKP];
    __shared__ int lentry[CE];
    __shared__ int laddr[CE];
    const int tid = threadIdx.x;
    const int base = blockIdx.x * CE;
    const int cnt = min(CE, E - base);

    int bk[EPT], en[EPT];
    #pragma unroll
    for (int i = 0; i < EPT; ++i) {
        int idx = i * 256 + tid;
        if (idx < cnt) {
            int s = src[base + idx];
            int d = dst[base + idx];
            bk[i] = d >> 8;
            en[i] = (s << 8) | (d & 255);
        } else bk[i] = -1;
    }
    hist[tid] = 0; hist[tid + 256] = 0;
    __syncthreads();
    #pragma unroll
    for (int i = 0; i < EPT; ++i)
        if (bk[i] >= 0) atomicAdd(&hist[bk[i]], 1);
    __syncthreads();
    // wave 0: exclusive scan of 512 counters (8 chunks of 64)
    if (tid < 64) {
        int run = 0;
        for (int c0 = 0; c0 < NBKP; c0 += 64) {
            int h = hist[c0 + tid];
            int v = h;
            #pragma unroll
            for (int off = 1; off < 64; off <<= 1) {
                int u = __shfl_up(v, off, 64);
                if (tid >= off) v += u;
            }
            lstart[c0 + tid] = run + v - h;
            run += __shfl(v, 63, 64);
        }
    }
    __syncthreads();
    // reserve bucket-relative space per non-empty bucket
    for (int b0 = tid; b0 < NBK; b0 += 256) {
        int h = hist[b0];
        gbase[b0] = h ? atomicAdd(&bucket_cnt[b0], h) : 0;
    }
    lcur[tid] = lstart[tid]; lcur[tid + 256] = lstart[tid + 256];
    __syncthreads();
    // place entries + their global destinations into LDS
    #pragma unroll
    for (int i = 0; i < EPT; ++i)
        if (bk[i] >= 0) {
            int off = atomicAdd(&lcur[bk[i]], 1);
            lentry[off] = en[i];
            int idx = gbase[bk[i]] + (off - lstart[bk[i]]);
            laddr[off] = (idx < CAP) ? (bk[i] * CAP + idx) : -1;  // overflow guard
        }
    __syncthreads();
    // copy out: consecutive j in same bucket -> consecutive global addresses
    for (int j = tid; j < cnt; j += 256) {
        int a = laddr[j];
        if (a >= 0) temp[a] = lentry[j];
    }
}

// ====================== scan 391 bucket counts -> bucket_base ======================
__global__ void k_scanb(const int* __restrict__ bucket_cnt, int* __restrict__ bucket_base, int nb) {
    __shared__ int s[512];
    int t = threadIdx.x;
    int own = (t < nb) ? bucket_cnt[t] : 0;
    s[t] = own;
    __syncthreads();
    for (int off = 1; off < 512; off <<= 1) {
        int v = (t >= off) ? s[t - off] : 0;
        __syncthreads();
        s[t] += v;
        __syncthreads();
    }
    if (t < nb) bucket_base[t] = s[t] - own;
}

// ====================== pass 2: per-node histogram + placement (MLP-4) ======================
__global__ __launch_bounds__(256) void k_place(
    const int* __restrict__ temp, const int* __restrict__ bucket_cnt,
    const int* __restrict__ bucket_base, int* __restrict__ csr_src,
    int* __restrict__ row_start, int* __restrict__ deg,
    float* __restrict__ dis, int n)
{
    __shared__ int cnt[256];
    __shared__ int s[256];
    __shared__ int pos[256];
    const int b = blockIdx.x;
    const int nbase = b << 8;
    const int tid = threadIdx.x;
    const int m = bucket_cnt[b];
    const size_t tbase = (size_t)b * CAP;
    cnt[tid] = 0;
    __syncthreads();
    for (int p0 = tid; p0 < m; p0 += 1024) {
        int p1 = p0 + 256, p2 = p0 + 512, p3 = p0 + 768;
        int e0 = temp[tbase + p0];
        int e1 = (p1 < m) ? temp[tbase + p1] : -1;
        int e2 = (p2 < m) ? temp[tbase + p2] : -1;
        int e3 = (p3 < m) ? temp[tbase + p3] : -1;
        atomicAdd(&cnt[e0 & 255], 1);
        if (e1 >= 0) atomicAdd(&cnt[e1 & 255], 1);
        if (e2 >= 0) atomicAdd(&cnt[e2 & 255], 1);
        if (e3 >= 0) atomicAdd(&cnt[e3 & 255], 1);
    }
    __syncthreads();
    int c = cnt[tid];
    s[tid] = c;
    __syncthreads();
    for (int off = 1; off < 256; off <<= 1) {
        int v = (tid >= off) ? s[tid - off] : 0;
        __syncthreads();
        s[tid] += v;
        __syncthreads();
    }
    int excl = s[tid] - c;
    int gb = bucket_base[b];
    if (nbase + tid < n) {
        row_start[nbase + tid] = gb + excl;
        deg[nbase + tid] = c;
        dis[nbase + tid] = rsqrtf((float)(c + 1));   // +1 self loop
    }
    pos[tid] = gb + excl;
    __syncthreads();
    for (int p0 = tid; p0 < m; p0 += 1024) {
        int p1 = p0 + 256, p2 = p0 + 512, p3 = p0 + 768;
        int e0 = temp[tbase + p0];
        int e1 = (p1 < m) ? temp[tbase + p1] : -1;
        int e2 = (p2 < m) ? temp[tbase + p2] : -1;
        int e3 = (p3 < m) ? temp[tbase + p3] : -1;
        int q0 = atomicAdd(&pos[e0 & 255], 1);
        csr_src[q0] = e0 >> 8;
        if (e1 >= 0) { int q = atomicAdd(&pos[e1 & 255], 1); csr_src[q] = e1 >> 8; }
        if (e2 >= 0) { int q = atomicAdd(&pos[e2 & 255], 1); csr_src[q] = e2 >> 8; }
        if (e3 >= 0) { int q = atomicAdd(&pos[e3 & 255], 1); csr_src[q] = e3 >> 8; }
    }
}

// ====================== GEMM1: hs1 = (x @ W1) * dis[row] ======================
__global__ __launch_bounds__(256) void k_gemm1(
    const float* __restrict__ x, const float* __restrict__ W1,
    const float* __restrict__ dis, float* __restrict__ hs1)
{
    __shared__ float xs[32][68];
    __shared__ float wsh[64][32];
    const int tid = threadIdx.x;
    const int r = tid >> 3;
    const int jg = tid & 7;
    const int row0 = blockIdx.x * 32;
    float4 acc = make_float4(0.f, 0.f, 0.f, 0.f);

    for (int kc = 0; kc < IN_DIM / 64; ++kc) {
        #pragma unroll
        for (int rep = 0; rep < 2; ++rep) {
            int idx = rep * 256 + tid;
            int xr = idx >> 4, c4 = idx & 15;
            float4 v = *(const float4*)&x[(size_t)(row0 + xr) * IN_DIM + kc * 64 + c4 * 4];
            *(float4*)&xs[xr][c4 * 4] = v;
        }
        #pragma unroll
        for (int rep = 0; rep < 2; ++rep) {
            int idx = rep * 256 + tid;
            int wr = idx >> 3, c4 = idx & 7;
            float4 v = *(const float4*)&W1[(size_t)(kc * 64 + wr) * HID + c4 * 4];
            *(float4*)&wsh[wr][c4 * 4] = v;
        }
        __syncthreads();
        #pragma unroll
        for (int k = 0; k < 64; ++k) {
            float xv = xs[r][k];
            float4 w = *(const float4*)&wsh[k][jg * 4];
            acc.x += xv * w.x; acc.y += xv * w.y; acc.z += xv * w.z; acc.w += xv * w.w;
        }
        __syncthreads();
    }
    int row = row0 + r;
    float s = dis[row];
    acc.x *= s; acc.y *= s; acc.z *= s; acc.w *= s;
    *(float4*)&hs1[(size_t)row * HID + jg * 4] = acc;
}

// ====================== agg1: pull-sum, 8-way MLP unroll ======================
__global__ __launch_bounds__(256) void k_agg1(
    const int* __restrict__ csr_src, const int* __restrict__ row_start,
    const int* __restrict__ deg, const float* __restrict__ hs1,
    float* __restrict__ agg1, int n)
{
    int lane = threadIdx.x & 31;
    int node = blockIdx.x * 8 + (threadIdx.x >> 5);
    if (node >= n) return;
    int dg = deg[node];
    int st = row_start[node];
    float a0 = hs1[(size_t)node * HID + lane];   // self loop
    float a1 = 0.f, a2 = 0.f, a3 = 0.f, a4 = 0.f, a5 = 0.f, a6 = 0.f, a7 = 0.f;
    for (int c0 = 0; c0 < dg; c0 += 32) {
        int e = c0 + lane;
        int sv = (e < dg) ? csr_src[st + e] : 0;
        int m = min(32, dg - c0);
        int i = 0;
        for (; i + 8 <= m; i += 8) {
            int s0 = __shfl(sv, i,     32);
            int s1 = __shfl(sv, i + 1, 32);
            int s2 = __shfl(sv, i + 2, 32);
            int s3 = __shfl(sv, i + 3, 32);
            int s4 = __shfl(sv, i + 4, 32);
            int s5 = __shfl(sv, i + 5, 32);
            int s6 = __shfl(sv, i + 6, 32);
            int s7 = __shfl(sv, i + 7, 32);
            float v0 = hs1[(size_t)s0 * HID + lane];
            float v1 = hs1[(size_t)s1 * HID + lane];
            float v2 = hs1[(size_t)s2 * HID + lane];
            float v3 = hs1[(size_t)s3 * HID + lane];
            float v4 = hs1[(size_t)s4 * HID + lane];
            float v5 = hs1[(size_t)s5 * HID + lane];
            float v6 = hs1[(size_t)s6 * HID + lane];
            float v7 = hs1[(size_t)s7 * HID + lane];
            a0 += v0; a1 += v1; a2 += v2; a3 += v3;
            a4 += v4; a5 += v5; a6 += v6; a7 += v7;
        }
        for (; i < m; ++i) {
            int s = __shfl(sv, i, 32);
            a0 += hs1[(size_t)s * HID + lane];
        }
    }
    agg1[(size_t)node * HID + lane] = ((a0 + a1) + (a2 + a3)) + ((a4 + a5) + (a6 + a7));
}

// ====================== GEMM2 ======================
__global__ __launch_bounds__(256) void k_gemm2(
    const float* __restrict__ agg1, const float* __restrict__ W2,
    const float* __restrict__ b1, const float* __restrict__ dis,
    float* __restrict__ hs2, int n)
{
    __shared__ float w2s[HID * OUT_DIM];
    __shared__ float b1s[HID];
    int tid = threadIdx.x;
    for (int i = tid; i < HID * OUT_DIM; i += 256) w2s[i] = W2[i];
    if (tid < HID) b1s[tid] = b1[tid];
    __syncthreads();
    int row = blockIdx.x * 256 + tid;
    if (row >= n) return;
    float ds = dis[row];
    float acc[OUT_DIM];
    #pragma unroll
    for (int j = 0; j < OUT_DIM; ++j) acc[j] = 0.f;
    #pragma unroll
    for (int k4 = 0; k4 < HID / 4; ++k4) {
        float4 v4 = *(const float4*)&agg1[(size_t)row * HID + k4 * 4];
        float vv[4] = { v4.x, v4.y, v4.z, v4.w };
        #pragma unroll
        for (int m = 0; m < 4; ++m) {
            int k = k4 * 4 + m;
            float v = fmaxf(ds * vv[m] + b1s[k], 0.f);
            #pragma unroll
            for (int j = 0; j < OUT_DIM; ++j) acc[j] += v * w2s[k * OUT_DIM + j];
        }
    }
    #pragma unroll
    for (int j = 0; j < OUT_DIM; ++j)
        hs2[(size_t)row * OUT_DIM + j] = acc[j] * ds;
}

// ====================== agg2: pull-sum, 8-way MLP unroll ======================
__global__ __launch_bounds__(256) void k_agg2(
    const int* __restrict__ csr_src, const int* __restrict__ row_start,
    const int* __restrict__ deg, const float* __restrict__ hs2,
    const float* __restrict__ dis, const float* __restrict__ b2,
    float* __restrict__ out, int n)
{
    int lane = threadIdx.x & 15;
    int node = blockIdx.x * 16 + (threadIdx.x >> 4);
    if (node >= n) return;
    int dg = deg[node];
    int st = row_start[node];
    float a0 = (lane < OUT_DIM) ? hs2[(size_t)node * OUT_DIM + lane] : 0.f;
    float a1 = 0.f, a2 = 0.f, a3 = 0.f, a4 = 0.f, a5 = 0.f, a6 = 0.f, a7 = 0.f;
    for (int c0 = 0; c0 < dg; c0 += 16) {
        int e = c0 + lane;
        int sv = (e < dg) ? csr_src[st + e] : 0;
        int m = min(16, dg - c0);
        int i = 0;
        for (; i + 8 <= m; i += 8) {
            int s0 = __shfl(sv, i,     16);
            int s1 = __shfl(sv, i + 1, 16);
            int s2 = __shfl(sv, i + 2, 16);
            int s3 = __shfl(sv, i + 3, 16);
            int s4 = __shfl(sv, i + 4, 16);
            int s5 = __shfl(sv, i + 5, 16);
            int s6 = __shfl(sv, i + 6, 16);
            int s7 = __shfl(sv, i + 7, 16);
            if (lane < OUT_DIM) {
                float v0 = hs2[(size_t)s0 * OUT_DIM + lane];
                float v1 = hs2[(size_t)s1 * OUT_DIM + lane];
                float v2 = hs2[(size_t)s2 * OUT_DIM + lane];
                float v3 = hs2[(size_t)s3 * OUT_DIM + lane];
                float v4 = hs2[(size_t)s4 * OUT_DIM + lane];
                float v5 = hs2[(size_t)s5 * OUT_DIM + lane];
                float v6 = hs2[(size_t)s6 * OUT_DIM + lane];
                float v7 = hs2[(size_t)s7 * OUT_DIM + lane];
                a0 += v0; a1 += v1; a2 += v2; a3 += v3;
                a4 += v4; a5 += v5; a6 += v6; a7 += v7;
            }
        }
        for (; i < m; ++i) {
            int s = __shfl(sv, i, 16);
            if (lane < OUT_DIM) a0 += hs2[(size_t)s * OUT_DIM + lane];
        }
    }
    if (lane < OUT_DIM)
        out[(size_t)node * OUT_DIM + lane] =
            dis[node] * (((a0 + a1) + (a2 + a3)) + ((a4 + a5) + (a6 + a7))) + b2[lane];
}

// ====================== launch ======================
extern "C" void kernel_launch(void* const* d_in, const int* in_sizes, int n_in,
                              void* d_out, int out_size, void* d_ws, size_t ws_size,
                              hipStream_t stream)
{
    const float* x  = (const float*)d_in[0];
    const int*   ei = (const int*)d_in[1];    // int64 inputs arrive as int32
    const float* W1 = (const float*)d_in[2];
    const float* b1 = (const float*)d_in[3];
    const float* W2 = (const float*)d_in[4];
    const float* b2 = (const float*)d_in[5];
    float* out = (float*)d_out;

    const int N = NN;
    const int E = in_sizes[1] / 2;
    const int* srcp = ei;
    const int* dstp = ei + E;
    const int NB = (N + 255) / 256;            // 391

    // workspace layout
    int* i0          = (int*)d_ws;
    int* bucket_cnt  = i0;                      // 512
    int* bucket_base = i0 + 512;                // 512
    int* row_start   = i0 + 1024;               // 100352
    int* deg         = i0 + 101376;             // 100352
    int* csr_src     = i0 + 201728;             // E
    float* f0        = (float*)d_ws + 201728 + 3200000;
    float* dis       = f0;                      // 100352
    float* hs1       = dis + 100352;            // N*32 (aliased as temp pre-gemm1)
    float* agg1      = hs1 + (size_t)N * HID;   // N*32
    float* hs2       = agg1 + (size_t)N * HID;  // N*12
    int* temp        = (int*)hs1;               // NBK*CAP = 4.0M ints

    // --- CSR build ---
    k_zerob<<<2, 256, 0, stream>>>(bucket_cnt);
    k_bin<<<(E + CE - 1) / CE, 256, 0, stream>>>(srcp, dstp, bucket_cnt, temp, E);
    k_scanb<<<1, 512, 0, stream>>>(bucket_cnt, bucket_base, NBK);
    k_place<<<NBK, 256, 0, stream>>>(temp, bucket_cnt, bucket_base,
                                     csr_src, row_start, deg, dis, N);

    // --- layer 1 ---
    k_gemm1<<<N / 32, 256, 0, stream>>>(x, W1, dis, hs1);
    k_agg1<<<(N + 7) / 8, 256, 0, stream>>>(csr_src, row_start, deg, hs1, agg1, N);

    // --- layer 2 ---
    k_gemm2<<<NB, 256, 0, stream>>>(agg1, W2, b1, dis, hs2, N);
    k_agg2<<<(N + 15) / 16, 256, 0, stream>>>(csr_src, row_start, deg, hs2, dis, b2, out, N);
}